// Round 4
// baseline (5937.485 us; speedup 1.0000x reference)
//
#include <hip/hip_runtime.h>
#include <hip/hip_bf16.h>
#include <cstdint>

// ---------------------------------------------------------------------------
// GemResNetBlock: two gauge-equivariant convs + Fourier ReLU + linear residual
#define NV     20000
#define NE     160000
#define IC1    16
#define OC     32
#define DIN    5      // 2*order+1, order=2 everywhere
#define NSLOT  49     // nonzeros of the 19-basis equivariant kernel
// ---------------------------------------------------------------------------
// Slot tables GENERATED AT COMPILE TIME by a literal transliteration of the
// reference build_kernel_basis.  (Verified: content matches two independent
// hand enumerations; rounds 1-3 output error came from the OUTPUT DTYPE,
// not this table — reference output is float32, not bf16.)
struct SlotTables {
    int n;
    int b[64], f[64], i[64], j[64];
    float v[64];
};

constexpr SlotTables make_slots() {
    SlotTables T{};
    float K[19][5][5][5] = {};   // [basis][freq][row i][col j]
    int nb = 0;
    const int BL = 2;
    auto add = [&](int f, const float (*cb)[2], const float (*sb)[2],
                   int m, int n) {
        if (f > BL) return;
        int r0 = (m == 0) ? 0 : (2 * m - 1), nr = (m == 0) ? 1 : 2;
        int c0 = (n == 0) ? 0 : (2 * n - 1), nc = (n == 0) ? 1 : 2;
        for (int a = 0; a < nr; a++)
            for (int bb = 0; bb < nc; bb++) {
                if (f == 0) {
                    K[nb][0][r0 + a][c0 + bb] = cb[a][bb];
                } else {
                    K[nb][2 * f - 1][r0 + a][c0 + bb] = cb[a][bb];
                    K[nb][2 * f    ][r0 + a][c0 + bb] = sb[a][bb];
                }
            }
        nb++;
    };
    const float ONE[2][2]  = {{1, 0}, {0, 0}};
    const float I2[2][2]   = {{1, 0}, {0, 1}};
    const float E2[2][2]   = {{0, -1}, {1, 0}};
    const float S2[2][2]   = {{1, 0}, {0, -1}};
    const float ES2[2][2]  = {{0, 1}, {1, 0}};     // E@S
    const float NS2[2][2]  = {{-1, 0}, {0, 1}};    // -S
    const float C10[2][2]  = {{1, 0}, {0, 0}};     // col [[1],[0]]
    const float C01[2][2]  = {{0, 0}, {1, 0}};     // col [[0],[1]]
    const float CM10[2][2] = {{-1, 0}, {0, 0}};    // col [[-1],[0]]
    const float R10[2][2]  = {{1, 0}, {0, 0}};     // row [[1,0]]
    const float R01[2][2]  = {{0, 1}, {0, 0}};     // row [[0,1]]
    const float RM10[2][2] = {{-1, 0}, {0, 0}};    // row [[-1,0]]

    for (int m = 0; m <= 2; m++)
        for (int n = 0; n <= 2; n++) {
            if (m == 0 && n == 0) {
                add(0, ONE, ONE, 0, 0);
            } else if (n == 0) {
                add(m, C10, C01, m, 0);
                add(m, C01, CM10, m, 0);
            } else if (m == 0) {
                add(n, R10, R01, 0, n);
                add(n, R01, RM10, 0, n);
            } else {
                int d = m - n;
                int f = d >= 0 ? d : -d;
                float sg = d >= 0 ? 1.f : -1.f;
                const float sgE[2][2]  = {{0, -sg}, {sg, 0}};   // sg*E
                const float msgI[2][2] = {{-sg, 0}, {0, -sg}};  // -sg*I
                add(f, I2, sgE, m, n);
                add(f, E2, msgI, m, n);
                add(m + n, S2, ES2, m, n);
                add(m + n, ES2, NS2, m, n);
            }
        }
    T.n = 0;
    for (int i = 0; i < 5; i++)
        for (int b = 0; b < nb; b++)
            for (int f = 0; f < 5; f++)
                for (int j = 0; j < 5; j++)
                    if (K[b][f][i][j] != 0.0f) {
                        T.b[T.n] = b; T.f[T.n] = f; T.i[T.n] = i;
                        T.j[T.n] = j; T.v[T.n] = K[b][f][i][j];
                        T.n++;
                    }
    return T;
}

constexpr SlotTables SL = make_slots();
static_assert(SL.n == NSLOT, "expect 49 kernel-basis nonzeros");
static_assert(SL.i[8] == 0 && SL.i[9] == 1 && SL.i[20] == 1 && SL.i[21] == 2 &&
              SL.i[32] == 2 && SL.i[33] == 3 && SL.i[40] == 3 && SL.i[41] == 4,
              "slot group boundaries");
static_assert(SL.b[1] == 1 && SL.f[1] == 1 && SL.j[1] == 1 && SL.v[1] == 1.0f,
              "slot 1");

// Build packed per-slot weights (fp32): wk[(c*NSLOT+s)*32+o] = float2(
//   v*W[b,ring0,o,c], v*W[b,ring1,o,c]).  W layout: [19][2][32][C].
template<int C>
__global__ __launch_bounds__(256) void build_wk(const float* __restrict__ W,
                                                float2* __restrict__ wk) {
    int t = blockIdx.x * 256 + threadIdx.x;
    if (t >= C * NSLOT * 32) return;
    int o = t & 31;
    int s = (t >> 5) % NSLOT;
    int c = (t >> 5) / NSLOT;
    int b = SL.b[s];
    float v = SL.v[s];
    float w0 = v * W[(size_t)((b * 2 + 0) * 32 + o) * C + c];
    float w1 = v * W[(size_t)((b * 2 + 1) * 32 + o) * C + c];
    wk[(c * NSLOT + s) * 32 + o] = make_float2(w0, w1);
}

// One thread per (edge, out-channel o).  Computes msg[e,o,0..4] and
// atomically scatters into y[dst].
template<int C>
__global__ __launch_bounds__(256) void edge_conv(const float* __restrict__ xin,
                                                 const int*   __restrict__ ei,
                                                 const float* __restrict__ pre,
                                                 const float* __restrict__ conn,
                                                 const float2* __restrict__ wk,
                                                 float* __restrict__ yout) {
    int t = blockIdx.x * 256 + threadIdx.x;
    int e = t >> 5;
    int o = t & 31;
    if (e >= NE) return;
    int dst = ei[e];           // edge_index[0] = dst
    int src = ei[NE + e];      // edge_index[1] = src
    float al = conn[e];
    float c1 = __cosf(al), s1 = __sinf(al);
    float c2 = c1 * c1 - s1 * s1, s2 = 2.0f * c1 * s1;
    float p[10];
    #pragma unroll
    for (int k = 0; k < 10; k++) p[k] = pre[(size_t)e * 10 + k];
    float acc[5] = {0.f, 0.f, 0.f, 0.f, 0.f};
    const float* xb = xin + (size_t)src * (C * DIN);
    for (int c = 0; c < C; c++) {
        float x0 = xb[c*5+0], x1 = xb[c*5+1], x2 = xb[c*5+2],
              x3 = xb[c*5+3], x4 = xb[c*5+4];
        float xt[5];
        xt[0] = x0;
        xt[1] = c1 * x1 - s1 * x2;   // rep_act, m=1
        xt[2] = s1 * x1 + c1 * x2;
        xt[3] = c2 * x3 - s2 * x4;   // rep_act, m=2
        xt[4] = s2 * x3 + c2 * x4;
        const float2* wrow = wk + (size_t)(c * NSLOT) * 32 + o;
        #pragma unroll
        for (int s = 0; s < NSLOT; s++) {
            float2 w = wrow[s * 32];
            float tt = fmaf(p[2 * SL.f[s] + 1], w.y, p[2 * SL.f[s]] * w.x);
            acc[SL.i[s]] = fmaf(tt, xt[SL.j[s]], acc[SL.i[s]]);
        }
    }
    float* yb = yout + ((size_t)dst * 32 + o) * 5;
    #pragma unroll
    for (int i = 0; i < 5; i++) atomicAdd(yb + i, acc[i]);
}

// Fourier-domain ReLU (7 samples, order 2).
__device__ __forceinline__ void fourier_relu(float d0, float d1, float d2,
                                             float d3, float d4, float* out5) {
    float o0 = 0, o1 = 0, o2 = 0, o3 = 0, o4 = 0;
    #pragma unroll
    for (int k = 0; k < 7; k++) {
        float th = (float)k * (6.28318530717958647692f / 7.0f);
        float ck = __cosf(th), sk = __sinf(th);
        float c2k = ck * ck - sk * sk, s2k = 2.f * ck * sk;
        float sv = d0 + ck * d1 + sk * d2 + c2k * d3 + s2k * d4;
        sv = fmaxf(sv, 0.f);
        o0 += sv; o1 += sv * ck; o2 += sv * sk; o3 += sv * c2k; o4 += sv * s2k;
    }
    const float i7 = 1.0f / 7.0f;
    out5[0] = o0 * i7; out5[1] = o1 * (2.f * i7); out5[2] = o2 * (2.f * i7);
    out5[3] = o3 * (2.f * i7); out5[4] = o4 * (2.f * i7);
}

__global__ __launch_bounds__(256) void relu_mid(float* __restrict__ y,
                                                const float* __restrict__ b1) {
    int t = blockIdx.x * 256 + threadIdx.x;     // v*32 + ch
    if (t >= NV * 32) return;
    int ch = t & 31;
    float* yb = y + (size_t)t * 5;
    float r[5];
    fourier_relu(yb[0] + b1[ch], yb[1], yb[2], yb[3], yb[4], r);
    #pragma unroll
    for (int d = 0; d < 5; d++) yb[d] = r[d];
}

__global__ __launch_bounds__(256) void final_k(const float* __restrict__ y2,
                                               const float* __restrict__ x,
                                               const float* __restrict__ Wl,
                                               const float* __restrict__ bl,
                                               const float* __restrict__ b2,
                                               float* __restrict__ out) {
    int t = blockIdx.x * 256 + threadIdx.x;     // v*32 + o
    if (t >= NV * 32) return;
    int o = t & 31;
    int v = t >> 5;
    float r0 = 0, r1 = 0, r2 = 0, r3 = 0, r4 = 0;
    const float* xb = x + (size_t)v * (IC1 * DIN);
    const float* wl = Wl + o * IC1;
    #pragma unroll
    for (int c = 0; c < IC1; c++) {
        float w = wl[c];
        r0 = fmaf(w, xb[c*5+0], r0); r1 = fmaf(w, xb[c*5+1], r1);
        r2 = fmaf(w, xb[c*5+2], r2); r3 = fmaf(w, xb[c*5+3], r3);
        r4 = fmaf(w, xb[c*5+4], r4);
    }
    float blo = bl[o];
    const float* yb = y2 + (size_t)t * 5;
    float d0 = yb[0] + b2[o] + r0 + blo;   // b2 on d=0 only; b_lin on all d
    float d1 = yb[1] + r1 + blo;
    float d2 = yb[2] + r2 + blo;
    float d3 = yb[3] + r3 + blo;
    float d4 = yb[4] + r4 + blo;
    float r[5];
    fourier_relu(d0, d1, d2, d3, d4, r);
    float* ob = out + (size_t)t * 5;
    #pragma unroll
    for (int d = 0; d < 5; d++) ob[d] = r[d];   // fp32 output (reference dtype)
}

extern "C" void kernel_launch(void* const* d_in, const int* in_sizes, int n_in,
                              void* d_out, int out_size, void* d_ws, size_t ws_size,
                              hipStream_t stream) {
    const float* x    = (const float*)d_in[0];
    const int*   ei   = (const int*)  d_in[1];
    const float* pre  = (const float*)d_in[2];
    const float* conn = (const float*)d_in[3];
    const float* W1   = (const float*)d_in[4];
    const float* b1   = (const float*)d_in[5];
    const float* W2   = (const float*)d_in[6];
    const float* b2   = (const float*)d_in[7];
    const float* Wl   = (const float*)d_in[8];
    const float* bl   = (const float*)d_in[9];
    float* out = (float*)d_out;

    // workspace layout (ws re-poisoned before every call -> re-init all of it)
    const size_t Y_BYTES = (size_t)NV * 32 * 5 * sizeof(float);     // 12.8 MB
    char* ws = (char*)d_ws;
    float*  y1  = (float*)(ws);
    float*  y2  = (float*)(ws + Y_BYTES);
    float2* wk1 = (float2*)(ws + 2 * Y_BYTES);
    float2* wk2 = (float2*)(ws + 2 * Y_BYTES + (size_t)IC1 * NSLOT * 32 * sizeof(float2));

    hipMemsetAsync(y1, 0, Y_BYTES, stream);
    hipMemsetAsync(y2, 0, Y_BYTES, stream);

    build_wk<IC1><<<(IC1 * NSLOT * 32 + 255) / 256, 256, 0, stream>>>(W1, wk1);
    build_wk<OC> <<<(OC  * NSLOT * 32 + 255) / 256, 256, 0, stream>>>(W2, wk2);

    edge_conv<IC1><<<(NE * 32) / 256, 256, 0, stream>>>(x,  ei, pre, conn, wk1, y1);
    relu_mid<<<(NV * 32) / 256, 256, 0, stream>>>(y1, b1);
    edge_conv<OC> <<<(NE * 32) / 256, 256, 0, stream>>>(y1, ei, pre, conn, wk2, y2);
    final_k<<<(NV * 32) / 256, 256, 0, stream>>>(y2, x, Wl, bl, b2, out);
}